// Round 8
// baseline (266.856 us; speedup 1.0000x reference)
//
#include <hip/hip_runtime.h>

// Problem constants: VOCAB=100000, EMB=300, B=2048, L=200, H=128, OUT=20
#define BB    2048
#define LL    200
#define EMB   300
#define HH    128
#define OUTD  20
#define NSRT  256
#define VOCAB 100000
#define RPW   (LL / 4)          // 50 rows per wave

// int8 quantized table layout in d_ws (ONLY if ws_size >= WS_NEED):
//   [0, 30,000,000)          : uint8 qtable, 300 B per row (channel c at byte c)
//   [30,000,000, 30,400,000) : float scale per row (dequant = q * scale)
#define QTAB_BYTES (VOCAB * 300)
#define SC_OFF     QTAB_BYTES
#define WS_NEED    (QTAB_BYTES + VOCAB * 4)

// ---------------- pass 1: per-row symmetric int8 quantization ----------------
// One wave per row. Lane j holds float4 slot j (channels 4j..4j+3); lanes 0..10
// also hold slot 64+j. Wave-allreduce max|v|, quantize, pack 4 int8 per uint.
__global__ __launch_bounds__(256) void quant_table(
    const float*   __restrict__ table,
    unsigned char* __restrict__ qt,
    float*         __restrict__ sc)
{
    const int row  = blockIdx.x * 4 + (threadIdx.x >> 6);
    const int lane = threadIdx.x & 63;
    const bool hb  = (lane < (EMB / 4 - 64));     // lane < 11

    const float4* rp = (const float4*)(table + (size_t)row * EMB);
    float4 fa = rp[lane];
    float4 fb = make_float4(0.f, 0.f, 0.f, 0.f);
    if (hb) fb = rp[64 + lane];

    float m = fmaxf(fmaxf(fabsf(fa.x), fabsf(fa.y)), fmaxf(fabsf(fa.z), fabsf(fa.w)));
    m = fmaxf(m, fmaxf(fmaxf(fabsf(fb.x), fabsf(fb.y)), fmaxf(fabsf(fb.z), fabsf(fb.w))));
    #pragma unroll
    for (int o = 32; o >= 1; o >>= 1)
        m = fmaxf(m, __shfl_xor(m, o, 64));

    const float inv   = (m > 0.f) ? 127.0f / m : 0.0f;
    const float scale = (m > 0.f) ? m / 127.0f : 0.0f;

    unsigned int* qrow = (unsigned int*)(qt + (size_t)row * 300);
    {
        const unsigned int q0 = (unsigned int)((int)rintf(fa.x * inv) & 0xff);
        const unsigned int q1 = (unsigned int)((int)rintf(fa.y * inv) & 0xff);
        const unsigned int q2 = (unsigned int)((int)rintf(fa.z * inv) & 0xff);
        const unsigned int q3 = (unsigned int)((int)rintf(fa.w * inv) & 0xff);
        qrow[lane] = q0 | (q1 << 8) | (q2 << 16) | (q3 << 24);
    }
    if (hb) {
        const unsigned int q0 = (unsigned int)((int)rintf(fb.x * inv) & 0xff);
        const unsigned int q1 = (unsigned int)((int)rintf(fb.y * inv) & 0xff);
        const unsigned int q2 = (unsigned int)((int)rintf(fb.z * inv) & 0xff);
        const unsigned int q3 = (unsigned int)((int)rintf(fb.w * inv) & 0xff);
        qrow[64 + lane] = q0 | (q1 << 8) | (q2 << 16) | (q3 << 24);
    }
    if (lane == 0) sc[row] = scale;
}

// ---------------- pass 2: fused gather (int8) + MLP ----------------
// R5 structure (proven 36 VGPR, full occupancy): one block per sample, 4 waves,
// bitonic-sorted indices (L3 locality), readlane -> SGPR row bases + scalar
// scale loads. Row = 75 uints; lane j reads uint j (channels 4j..4j+3, same
// channel->lane map as the fp32 float4 version), lanes 0..10 also uint 64+j.
__global__ __launch_bounds__(256) void fused_dnn_q8(
    const int*           __restrict__ x,
    const int*           __restrict__ lengths,
    const unsigned char* __restrict__ qt,
    const float*         __restrict__ sc,
    const float*         __restrict__ W1,
    const float*         __restrict__ b1,
    const float*         __restrict__ W2,
    const float*         __restrict__ b2,
    float*               __restrict__ out)
{
    __shared__ int    idx_s[NSRT];
    __shared__ float4 part_s[4][76];
    __shared__ float  rep_s[EMB];
    __shared__ float  h_part[2][HH];
    __shared__ float  h_s[HH];

    const int b    = blockIdx.x;
    const int t    = threadIdx.x;
    const int w    = t >> 6;
    const int lane = t & 63;

    idx_s[t] = (t < LL) ? x[b * LL + t] : 0x7FFFFFFF;
    __syncthreads();

    #pragma unroll
    for (int k = 2; k <= NSRT; k <<= 1) {
        #pragma unroll
        for (int j = k >> 1; j > 0; j >>= 1) {
            const int ixj = t ^ j;
            if (ixj > t) {
                const int a0 = idx_s[t];
                const int a1 = idx_s[ixj];
                const bool up = ((t & k) == 0);
                if ((a0 > a1) == up) { idx_s[t] = a1; idx_s[ixj] = a0; }
            }
            __syncthreads();
        }
    }

    const int myidx = (lane < RPW) ? idx_s[w + 4 * lane] : 0;

    float4 acc_a = make_float4(0.f, 0.f, 0.f, 0.f);
    float4 acc_b = make_float4(0.f, 0.f, 0.f, 0.f);
    const bool hasb = (lane < (EMB / 4 - 64));   // lane < 11

    #pragma unroll 4
    for (int i = 0; i < RPW; ++i) {
        const int ridx = __builtin_amdgcn_readlane(myidx, i);   // SGPR-uniform
        const unsigned int* qrow = (const unsigned int*)(qt + (size_t)ridx * 300);
        const float s = sc[ridx];                               // scalar load
        const unsigned int ua = qrow[lane];
        acc_a.x = fmaf(s, (float)(signed char)(ua      ), acc_a.x);
        acc_a.y = fmaf(s, (float)(signed char)(ua >>  8), acc_a.y);
        acc_a.z = fmaf(s, (float)(signed char)(ua >> 16), acc_a.z);
        acc_a.w = fmaf(s, (float)(signed char)(ua >> 24), acc_a.w);
        if (hasb) {
            const unsigned int ub = qrow[64 + lane];
            acc_b.x = fmaf(s, (float)(signed char)(ub      ), acc_b.x);
            acc_b.y = fmaf(s, (float)(signed char)(ub >>  8), acc_b.y);
            acc_b.z = fmaf(s, (float)(signed char)(ub >> 16), acc_b.z);
            acc_b.w = fmaf(s, (float)(signed char)(ub >> 24), acc_b.w);
        }
    }

    part_s[w][lane] = acc_a;
    if (hasb) part_s[w][64 + lane] = acc_b;
    __syncthreads();

    const float inv_len = 1.0f / (float)lengths[b];
    const float* ps = (const float*)part_s;      // [4][304] floats
    {
        float sv = ps[t] + ps[304 + t] + ps[608 + t] + ps[912 + t];
        rep_s[t] = sv * inv_len;
    }
    if (t < (EMB - 256)) {
        int c = 256 + t;
        float sv = ps[c] + ps[304 + c] + ps[608 + c] + ps[912 + c];
        rep_s[c] = sv * inv_len;
    }
    __syncthreads();

    {
        const int half = t >> 7;
        const int col  = t & 127;
        float hacc = (half == 0) ? b1[col] : 0.0f;
        const int k0 = half * (EMB / 2);
        #pragma unroll 5
        for (int k = k0; k < k0 + EMB / 2; ++k)
            hacc = fmaf(rep_s[k], W1[k * HH + col], hacc);
        h_part[half][col] = hacc;
    }
    __syncthreads();
    if (t < HH)
        h_s[t] = fmaxf(h_part[0][t] + h_part[1][t], 0.0f);
    __syncthreads();

    if (t < OUTD) {
        float oacc = b2[t];
        #pragma unroll
        for (int k = 0; k < HH; ++k)
            oacc = fmaf(h_s[k], W2[k * OUTD + t], oacc);
        out[b * OUTD + t] = oacc;
    }
}

// ---------------- fallback: proven fp32 R5 kernel (no workspace use) ----------------
__global__ __launch_bounds__(256) void fused_dnn_f32(
    const int*   __restrict__ x,
    const int*   __restrict__ lengths,
    const float* __restrict__ table,
    const float* __restrict__ W1,
    const float* __restrict__ b1,
    const float* __restrict__ W2,
    const float* __restrict__ b2,
    float*       __restrict__ out)
{
    __shared__ int    idx_s[NSRT];
    __shared__ float4 part_s[4][76];
    __shared__ float  rep_s[EMB];
    __shared__ float  h_part[2][HH];
    __shared__ float  h_s[HH];

    const int b    = blockIdx.x;
    const int t    = threadIdx.x;
    const int w    = t >> 6;
    const int lane = t & 63;

    idx_s[t] = (t < LL) ? x[b * LL + t] : 0x7FFFFFFF;
    __syncthreads();

    #pragma unroll
    for (int k = 2; k <= NSRT; k <<= 1) {
        #pragma unroll
        for (int j = k >> 1; j > 0; j >>= 1) {
            const int ixj = t ^ j;
            if (ixj > t) {
                const int a0 = idx_s[t];
                const int a1 = idx_s[ixj];
                const bool up = ((t & k) == 0);
                if ((a0 > a1) == up) { idx_s[t] = a1; idx_s[ixj] = a0; }
            }
            __syncthreads();
        }
    }

    const int myidx = (lane < RPW) ? idx_s[w + 4 * lane] : 0;

    float4 acc_a = make_float4(0.f, 0.f, 0.f, 0.f);
    float4 acc_b = make_float4(0.f, 0.f, 0.f, 0.f);
    const bool hasb = (lane < (EMB / 4 - 64));

    #pragma unroll 5
    for (int i = 0; i < RPW; ++i) {
        const int ridx = __builtin_amdgcn_readlane(myidx, i);
        const float4* row = (const float4*)(table + (size_t)ridx * EMB);
        float4 va = row[lane];
        acc_a.x += va.x; acc_a.y += va.y; acc_a.z += va.z; acc_a.w += va.w;
        if (hasb) {
            float4 vb = row[64 + lane];
            acc_b.x += vb.x; acc_b.y += vb.y; acc_b.z += vb.z; acc_b.w += vb.w;
        }
    }

    part_s[w][lane] = acc_a;
    if (hasb) part_s[w][64 + lane] = acc_b;
    __syncthreads();

    const float inv_len = 1.0f / (float)lengths[b];
    const float* ps = (const float*)part_s;
    {
        float sv = ps[t] + ps[304 + t] + ps[608 + t] + ps[912 + t];
        rep_s[t] = sv * inv_len;
    }
    if (t < (EMB - 256)) {
        int c = 256 + t;
        float sv = ps[c] + ps[304 + c] + ps[608 + c] + ps[912 + c];
        rep_s[c] = sv * inv_len;
    }
    __syncthreads();

    {
        const int half = t >> 7;
        const int col  = t & 127;
        float hacc = (half == 0) ? b1[col] : 0.0f;
        const int k0 = half * (EMB / 2);
        #pragma unroll 5
        for (int k = k0; k < k0 + EMB / 2; ++k)
            hacc = fmaf(rep_s[k], W1[k * HH + col], hacc);
        h_part[half][col] = hacc;
    }
    __syncthreads();
    if (t < HH)
        h_s[t] = fmaxf(h_part[0][t] + h_part[1][t], 0.0f);
    __syncthreads();

    if (t < OUTD) {
        float oacc = b2[t];
        #pragma unroll
        for (int k = 0; k < HH; ++k)
            oacc = fmaf(h_s[k], W2[k * OUTD + t], oacc);
        out[b * OUTD + t] = oacc;
    }
}

extern "C" void kernel_launch(void* const* d_in, const int* in_sizes, int n_in,
                              void* d_out, int out_size, void* d_ws, size_t ws_size,
                              hipStream_t stream) {
    const int*   x       = (const int*)  d_in[0];
    const int*   lengths = (const int*)  d_in[1];
    const float* table   = (const float*)d_in[2];
    const float* W1      = (const float*)d_in[3];
    const float* b1      = (const float*)d_in[4];
    const float* W2      = (const float*)d_in[5];
    const float* b2      = (const float*)d_in[6];
    float*       out     = (float*)d_out;

    if (ws_size >= (size_t)WS_NEED) {
        unsigned char* qt = (unsigned char*)d_ws;
        float*         sc = (float*)((char*)d_ws + SC_OFF);
        quant_table<<<VOCAB / 4, 256, 0, stream>>>(table, qt, sc);
        fused_dnn_q8<<<BB, 256, 0, stream>>>(x, lengths, qt, sc, W1, b1, W2, b2, out);
    } else {
        fused_dnn_f32<<<BB, 256, 0, stream>>>(x, lengths, table, W1, b1, W2, b2, out);
    }
}

// Round 9
// 262.963 us; speedup vs baseline: 1.0148x; 1.0148x over previous
//
#include <hip/hip_runtime.h>

// Problem constants: VOCAB=100000, EMB=300, B=2048, L=200, H=128, OUT=20
#define BB    2048
#define LL    200
#define EMB   300
#define HH    128
#define OUTD  20
#define NSRT  256
#define VOCAB 100000
#define RPW   (LL / 4)          // 50 rows per wave

// Quantized table in d_ws: 304 B per row = 75 uints of packed int8 (channels
// 0..299, channel c at byte c) + 1 float scale in bytes 300..303.
// Row stride 304 = 19*16 -> every row is 19 aligned uint4s.
#define ROWB    304
#define WS_NEED (VOCAB * ROWB)   // 30,400,000 B — same as R8 (proven to fit)

// ---------------- pass 1: per-row symmetric int8 quantization ----------------
// One wave per row; lane j holds float4 slot j (channels 4j..4j+3), lanes 0..10
// also slot 64+j. Wave-allreduce max|v|; pack; lane 0 embeds the scale.
__global__ __launch_bounds__(256) void quant_table(
    const float*   __restrict__ table,
    unsigned char* __restrict__ qt)
{
    const int row  = blockIdx.x * 4 + (threadIdx.x >> 6);
    const int lane = threadIdx.x & 63;
    const bool hb  = (lane < (EMB / 4 - 64));     // lane < 11

    const float4* rp = (const float4*)(table + (size_t)row * EMB);
    float4 fa = rp[lane];
    float4 fb = make_float4(0.f, 0.f, 0.f, 0.f);
    if (hb) fb = rp[64 + lane];

    float m = fmaxf(fmaxf(fabsf(fa.x), fabsf(fa.y)), fmaxf(fabsf(fa.z), fabsf(fa.w)));
    m = fmaxf(m, fmaxf(fmaxf(fabsf(fb.x), fabsf(fb.y)), fmaxf(fabsf(fb.z), fabsf(fb.w))));
    #pragma unroll
    for (int o = 32; o >= 1; o >>= 1)
        m = fmaxf(m, __shfl_xor(m, o, 64));

    const float inv   = (m > 0.f) ? 127.0f / m : 0.0f;
    const float scale = (m > 0.f) ? m / 127.0f : 0.0f;

    unsigned int* qrow = (unsigned int*)(qt + (size_t)row * ROWB);
    {
        const unsigned int q0 = (unsigned int)((int)rintf(fa.x * inv) & 0xff);
        const unsigned int q1 = (unsigned int)((int)rintf(fa.y * inv) & 0xff);
        const unsigned int q2 = (unsigned int)((int)rintf(fa.z * inv) & 0xff);
        const unsigned int q3 = (unsigned int)((int)rintf(fa.w * inv) & 0xff);
        qrow[lane] = q0 | (q1 << 8) | (q2 << 16) | (q3 << 24);
    }
    if (hb) {
        const unsigned int q0 = (unsigned int)((int)rintf(fb.x * inv) & 0xff);
        const unsigned int q1 = (unsigned int)((int)rintf(fb.y * inv) & 0xff);
        const unsigned int q2 = (unsigned int)((int)rintf(fb.z * inv) & 0xff);
        const unsigned int q3 = (unsigned int)((int)rintf(fb.w * inv) & 0xff);
        qrow[64 + lane] = q0 | (q1 << 8) | (q2 << 16) | (q3 << 24);
    }
    if (lane == 0) qrow[75] = __float_as_uint(scale);
}

// ---------------- pass 2: fused gather (q8, 3 rows per load instr) + MLP ----------------
// One block per sample, 4 waves. Lanes 0..56 = 3 groups of 19; group r loads
// row slot j=3i+r with ONE dwordx4 (lane g of the group takes bytes 16g..16g+15;
// g=18's .w is the row scale, broadcast to the group via __shfl). 17 load
// instructions per wave instead of 100 — attacks the measured ~65 cyc/instr
// miss-path cost that R8 showed is the gather bottleneck (not bytes/lines).
__global__ __launch_bounds__(256, 6) void fused_dnn_q8(
    const int*           __restrict__ x,
    const int*           __restrict__ lengths,
    const unsigned char* __restrict__ qt,
    const float*         __restrict__ W1,
    const float*         __restrict__ b1,
    const float*         __restrict__ W2,
    const float*         __restrict__ b2,
    float*               __restrict__ out)
{
    __shared__ int    idx_s[NSRT];
    __shared__ float4 part4[12][76];    // [wave*3+group][float4-chan 0..75]
    __shared__ float  rep_s[EMB];
    __shared__ float  h_part[2][HH];
    __shared__ float  h_s[HH];

    const int b = blockIdx.x;
    const int t = threadIdx.x;
    const int w = t >> 6;
    const int l = t & 63;

    idx_s[t] = (t < LL) ? x[b * LL + t] : 0x7FFFFFFF;
    __syncthreads();

    // ---- bitonic sort ascending (L3 locality across co-resident blocks)
    #pragma unroll
    for (int k = 2; k <= NSRT; k <<= 1) {
        #pragma unroll
        for (int j = k >> 1; j > 0; j >>= 1) {
            const int ixj = t ^ j;
            if (ixj > t) {
                const int a0 = idx_s[t];
                const int a1 = idx_s[ixj];
                const bool up = ((t & k) == 0);
                if ((a0 > a1) == up) { idx_s[t] = a1; idx_s[ixj] = a0; }
            }
            __syncthreads();
        }
    }

    // lane partition: groups of 19; lanes 57..63 shadow group 2 (weight 0)
    const bool active = (l < 57);
    const int  rr = active ? (l / 19) : 2;       // group 0..2
    const int  g  = active ? (l % 19) : (l - 57); // uint4 slot within row

    float4 acc0 = make_float4(0.f,0.f,0.f,0.f);
    float4 acc1 = make_float4(0.f,0.f,0.f,0.f);
    float4 acc2 = make_float4(0.f,0.f,0.f,0.f);
    float4 acc3 = make_float4(0.f,0.f,0.f,0.f);
    const int slane = rr * 19 + 18;              // scale-holder lane (<=56)

    #pragma unroll
    for (int i = 0; i < 17; ++i) {
        const int j  = 3 * i + rr;               // row slot within wave
        const int jc = (j < RPW) ? j : (RPW - 1);
        const int ridx = idx_s[w + 4 * jc];      // wave-interleaved sorted order
        const uint4 d = *(const uint4*)(qt + (size_t)ridx * ROWB + (g << 4));

        float sva = __shfl(__uint_as_float(d.w), slane, 64);
        const float sv  = (active && (j < RPW)) ? sva : 0.0f;
        const float sv3 = (g == 18) ? 0.0f : sv; // slot 75 is the scale, not data

        acc0.x = fmaf(sv, (float)(signed char)(d.x       ), acc0.x);
        acc0.y = fmaf(sv, (float)(signed char)(d.x >>  8 ), acc0.y);
        acc0.z = fmaf(sv, (float)(signed char)(d.x >> 16 ), acc0.z);
        acc0.w = fmaf(sv, (float)(signed char)(d.x >> 24 ), acc0.w);
        acc1.x = fmaf(sv, (float)(signed char)(d.y       ), acc1.x);
        acc1.y = fmaf(sv, (float)(signed char)(d.y >>  8 ), acc1.y);
        acc1.z = fmaf(sv, (float)(signed char)(d.y >> 16 ), acc1.z);
        acc1.w = fmaf(sv, (float)(signed char)(d.y >> 24 ), acc1.w);
        acc2.x = fmaf(sv, (float)(signed char)(d.z       ), acc2.x);
        acc2.y = fmaf(sv, (float)(signed char)(d.z >>  8 ), acc2.y);
        acc2.z = fmaf(sv, (float)(signed char)(d.z >> 16 ), acc2.z);
        acc2.w = fmaf(sv, (float)(signed char)(d.z >> 24 ), acc2.w);
        acc3.x = fmaf(sv3,(float)(signed char)(d.w       ), acc3.x);
        acc3.y = fmaf(sv3,(float)(signed char)(d.w >>  8 ), acc3.y);
        acc3.z = fmaf(sv3,(float)(signed char)(d.w >> 16 ), acc3.z);
        acc3.w = fmaf(sv3,(float)(signed char)(d.w >> 24 ), acc3.w);
    }

    if (active) {
        const int p = w * 3 + rr;                // 0..11
        part4[p][g * 4 + 0] = acc0;
        part4[p][g * 4 + 1] = acc1;
        part4[p][g * 4 + 2] = acc2;
        part4[p][g * 4 + 3] = acc3;
    }
    __syncthreads();

    // ---- reduce 12 partials + scale by 1/len
    const float inv_len = 1.0f / (float)lengths[b];
    const float* pf = (const float*)part4;       // [12][304] floats
    {
        float s = 0.f;
        #pragma unroll
        for (int p = 0; p < 12; ++p) s += pf[p * 304 + t];
        rep_s[t] = s * inv_len;                  // channels 0..255
    }
    if (t < (EMB - 256)) {                       // channels 256..299
        const int c = 256 + t;
        float s = 0.f;
        #pragma unroll
        for (int p = 0; p < 12; ++p) s += pf[p * 304 + c];
        rep_s[c] = s * inv_len;
    }
    __syncthreads();

    // ---- h = relu(rep @ W1 + b1), split-k across the two half-blocks
    {
        const int half = t >> 7;
        const int col  = t & 127;
        float hacc = (half == 0) ? b1[col] : 0.0f;
        const int k0 = half * (EMB / 2);
        #pragma unroll 5
        for (int k = k0; k < k0 + EMB / 2; ++k)
            hacc = fmaf(rep_s[k], W1[k * HH + col], hacc);
        h_part[half][col] = hacc;
    }
    __syncthreads();
    if (t < HH)
        h_s[t] = fmaxf(h_part[0][t] + h_part[1][t], 0.0f);
    __syncthreads();

    // ---- logits = h @ W2 + b2
    if (t < OUTD) {
        float oacc = b2[t];
        #pragma unroll
        for (int k = 0; k < HH; ++k)
            oacc = fmaf(h_s[k], W2[k * OUTD + t], oacc);
        out[b * OUTD + t] = oacc;
    }
}

// ---------------- fallback: proven fp32 R5 kernel (no workspace use) ----------------
__global__ __launch_bounds__(256) void fused_dnn_f32(
    const int*   __restrict__ x,
    const int*   __restrict__ lengths,
    const float* __restrict__ table,
    const float* __restrict__ W1,
    const float* __restrict__ b1,
    const float* __restrict__ W2,
    const float* __restrict__ b2,
    float*       __restrict__ out)
{
    __shared__ int    idx_s[NSRT];
    __shared__ float4 part_s[4][76];
    __shared__ float  rep_s[EMB];
    __shared__ float  h_part[2][HH];
    __shared__ float  h_s[HH];

    const int b    = blockIdx.x;
    const int t    = threadIdx.x;
    const int w    = t >> 6;
    const int lane = t & 63;

    idx_s[t] = (t < LL) ? x[b * LL + t] : 0x7FFFFFFF;
    __syncthreads();

    #pragma unroll
    for (int k = 2; k <= NSRT; k <<= 1) {
        #pragma unroll
        for (int j = k >> 1; j > 0; j >>= 1) {
            const int ixj = t ^ j;
            if (ixj > t) {
                const int a0 = idx_s[t];
                const int a1 = idx_s[ixj];
                const bool up = ((t & k) == 0);
                if ((a0 > a1) == up) { idx_s[t] = a1; idx_s[ixj] = a0; }
            }
            __syncthreads();
        }
    }

    const int myidx = (lane < RPW) ? idx_s[w + 4 * lane] : 0;

    float4 acc_a = make_float4(0.f, 0.f, 0.f, 0.f);
    float4 acc_b = make_float4(0.f, 0.f, 0.f, 0.f);
    const bool hasb = (lane < (EMB / 4 - 64));

    #pragma unroll 5
    for (int i = 0; i < RPW; ++i) {
        const int ridx = __builtin_amdgcn_readlane(myidx, i);
        const float4* row = (const float4*)(table + (size_t)ridx * EMB);
        float4 va = row[lane];
        acc_a.x += va.x; acc_a.y += va.y; acc_a.z += va.z; acc_a.w += va.w;
        if (hasb) {
            float4 vb = row[64 + lane];
            acc_b.x += vb.x; acc_b.y += vb.y; acc_b.z += vb.z; acc_b.w += vb.w;
        }
    }

    part_s[w][lane] = acc_a;
    if (hasb) part_s[w][64 + lane] = acc_b;
    __syncthreads();

    const float inv_len = 1.0f / (float)lengths[b];
    const float* ps = (const float*)part_s;
    {
        float sv = ps[t] + ps[304 + t] + ps[608 + t] + ps[912 + t];
        rep_s[t] = sv * inv_len;
    }
    if (t < (EMB - 256)) {
        int c = 256 + t;
        float sv = ps[c] + ps[304 + c] + ps[608 + c] + ps[912 + c];
        rep_s[c] = sv * inv_len;
    }
    __syncthreads();

    {
        const int half = t >> 7;
        const int col  = t & 127;
        float hacc = (half == 0) ? b1[col] : 0.0f;
        const int k0 = half * (EMB / 2);
        #pragma unroll 5
        for (int k = k0; k < k0 + EMB / 2; ++k)
            hacc = fmaf(rep_s[k], W1[k * HH + col], hacc);
        h_part[half][col] = hacc;
    }
    __syncthreads();
    if (t < HH)
        h_s[t] = fmaxf(h_part[0][t] + h_part[1][t], 0.0f);
    __syncthreads();

    if (t < OUTD) {
        float oacc = b2[t];
        #pragma unroll
        for (int k = 0; k < HH; ++k)
            oacc = fmaf(h_s[k], W2[k * OUTD + t], oacc);
        out[b * OUTD + t] = oacc;
    }
}

extern "C" void kernel_launch(void* const* d_in, const int* in_sizes, int n_in,
                              void* d_out, int out_size, void* d_ws, size_t ws_size,
                              hipStream_t stream) {
    const int*   x       = (const int*)  d_in[0];
    const int*   lengths = (const int*)  d_in[1];
    const float* table   = (const float*)d_in[2];
    const float* W1      = (const float*)d_in[3];
    const float* b1      = (const float*)d_in[4];
    const float* W2      = (const float*)d_in[5];
    const float* b2      = (const float*)d_in[6];
    float*       out     = (float*)d_out;

    if (ws_size >= (size_t)WS_NEED) {
        unsigned char* qt = (unsigned char*)d_ws;
        quant_table<<<VOCAB / 4, 256, 0, stream>>>(table, qt);
        fused_dnn_q8<<<BB, 256, 0, stream>>>(x, lengths, qt, W1, b1, W2, b2, out);
    } else {
        fused_dnn_f32<<<BB, 256, 0, stream>>>(x, lengths, table, W1, b1, W2, b2, out);
    }
}

// Round 10
// 247.429 us; speedup vs baseline: 1.0785x; 1.0628x over previous
//
#include <hip/hip_runtime.h>

// Problem constants: VOCAB=100000, EMB=300, B=2048, L=200, H=128, OUT=20
#define BB    2048
#define LL    200
#define EMB   300
#define HH    128
#define OUTD  20
#define NSRT  256
#define VOCAB 100000
#define RPW   (LL / 4)          // 50 rows per wave

// d_ws layout: projected+quantized table T'q = quant(table @ W1):
//   [0, 12.8M)   : int8 rows, 128 B per row (col n at byte n) — ONE cache line
//   [12.8M, +400K): float per-row scale
#define QT_BYTES ((size_t)VOCAB * HH)          // 12,800,000
#define SC_OFF   QT_BYTES
#define WS_NEED  (QT_BYTES + (size_t)VOCAB * 4)

typedef short  bf16x8 __attribute__((ext_vector_type(8)));
typedef float  f32x4  __attribute__((ext_vector_type(4)));

__device__ __forceinline__ unsigned short f2bf(float x) {
    unsigned int u = __float_as_uint(x);
    return (unsigned short)((u + 0x7fffu + ((u >> 16) & 1u)) >> 16);   // RNE
}

// ---------------- pass A: T' = table @ W1, int8-quantized per row ----------------
// Grid 391 x 256 thr. Block = 256 table rows; wave = 64 rows = 4 m-tiles of 16.
// MFMA f32_16x16x32_bf16. B (W1, 300x128) staged in LDS pre-swizzled into
// B-fragment order (lane n=l&15 holds 8 k-contiguous bf16 — gemm_bt layout),
// two phases of 5 k-steps (40 KB LDS, reused by the epilogue). K tail (300->320)
// zero-padded on both operands.
__global__ __launch_bounds__(256) void proj_quant(
    const float* __restrict__ table,
    const float* __restrict__ W1,
    unsigned char* __restrict__ qt,
    float* __restrict__ sc)
{
    __shared__ __align__(16) unsigned char bstage[40960];

    const int t    = threadIdx.x;
    const int w    = t >> 6;
    const int lane = t & 63;
    const int quad = lane >> 4;
    const int c16  = lane & 15;
    const int m_base = blockIdx.x * 256 + w * 64;

    f32x4 acc[4][8];
    #pragma unroll
    for (int mt = 0; mt < 4; ++mt)
        #pragma unroll
        for (int nt = 0; nt < 8; ++nt)
            acc[mt][nt] = (f32x4){0.f, 0.f, 0.f, 0.f};

    #pragma unroll
    for (int ph = 0; ph < 2; ++ph) {
        __syncthreads();
        // stage B-fragments for k-steps ph*5 .. ph*5+4
        #pragma unroll
        for (int i = 0; i < 10; ++i) {
            const int s   = t + 256 * i;          // 0..2559
            const int ktl = s >> 9;
            const int rem = s & 511;
            const int nt  = rem >> 6;
            const int ls  = rem & 63;
            const int q   = ls >> 4;
            const int n   = nt * 16 + (ls & 15);
            const int k0  = (ph * 5 + ktl) * 32 + q * 8;
            unsigned int pk[4];
            #pragma unroll
            for (int jj = 0; jj < 4; ++jj) {
                const int ka = k0 + 2 * jj, kb = ka + 1;
                const float f0 = (ka < EMB) ? W1[ka * HH + n] : 0.f;
                const float f1 = (kb < EMB) ? W1[kb * HH + n] : 0.f;
                pk[jj] = (unsigned int)f2bf(f0) | ((unsigned int)f2bf(f1) << 16);
            }
            *(uint4*)(bstage + (size_t)s * 16) = make_uint4(pk[0], pk[1], pk[2], pk[3]);
        }
        __syncthreads();

        #pragma unroll
        for (int ktl = 0; ktl < 5; ++ktl) {
            const int kt = ph * 5 + ktl;
            bf16x8 bf[8];
            #pragma unroll
            for (int nt = 0; nt < 8; ++nt)
                bf[nt] = *(const bf16x8*)(bstage + ((ktl * 8 + nt) * 64 + lane) * 16);

            #pragma unroll
            for (int mt = 0; mt < 4; ++mt) {
                int row = m_base + mt * 16 + c16;
                if (row > VOCAB - 1) row = VOCAB - 1;
                const float* base = table + (size_t)row * EMB;
                const int k0 = kt * 32 + quad * 8;
                float f[8];
                if (k0 + 8 <= EMB) {
                    float4 a = *(const float4*)(base + k0);
                    float4 b = *(const float4*)(base + k0 + 4);
                    f[0]=a.x; f[1]=a.y; f[2]=a.z; f[3]=a.w;
                    f[4]=b.x; f[5]=b.y; f[6]=b.z; f[7]=b.w;
                } else if (k0 < EMB) {                    // k0 == 296
                    float4 a = *(const float4*)(base + k0);
                    f[0]=a.x; f[1]=a.y; f[2]=a.z; f[3]=a.w;
                    f[4]=0.f; f[5]=0.f; f[6]=0.f; f[7]=0.f;
                } else {
                    #pragma unroll
                    for (int jj = 0; jj < 8; ++jj) f[jj] = 0.f;
                }
                bf16x8 af;
                #pragma unroll
                for (int jj = 0; jj < 8; ++jj) af[jj] = (short)f2bf(f[jj]);

                #pragma unroll
                for (int nt = 0; nt < 8; ++nt)
                    acc[mt][nt] = __builtin_amdgcn_mfma_f32_16x16x32_bf16(
                        af, bf[nt], acc[mt][nt], 0, 0, 0);
            }
        }
    }

    // ---- epilogue: per-row absmax -> int8 quantize -> coalesced store
    __syncthreads();                          // bstage dead; reuse as staging
    unsigned char* st = bstage + w * 8192;    // 64 rows x 128 B per wave

    #pragma unroll
    for (int mt = 0; mt < 4; ++mt) {
        float mx[4];
        #pragma unroll
        for (int r = 0; r < 4; ++r) {
            float m = 0.f;
            #pragma unroll
            for (int nt = 0; nt < 8; ++nt) m = fmaxf(m, fabsf(acc[mt][nt][r]));
            mx[r] = m;
        }
        #pragma unroll
        for (int o = 1; o < 16; o <<= 1)
            #pragma unroll
            for (int r = 0; r < 4; ++r)
                mx[r] = fmaxf(mx[r], __shfl_xor(mx[r], o, 64));

        float inv[4], scl[4];
        #pragma unroll
        for (int r = 0; r < 4; ++r) {
            scl[r] = mx[r] * (1.0f / 127.0f);
            inv[r] = (mx[r] > 0.f) ? 127.0f / mx[r] : 0.f;
        }
        #pragma unroll
        for (int r = 0; r < 4; ++r)
            #pragma unroll
            for (int nt = 0; nt < 8; ++nt) {
                const int q = (int)rintf(acc[mt][nt][r] * inv[r]);
                st[(mt * 16 + quad * 4 + r) * 128 + nt * 16 + c16] =
                    (unsigned char)(q & 0xff);
            }
        if (c16 == 0) {
            #pragma unroll
            for (int r = 0; r < 4; ++r) {
                const int grow = m_base + mt * 16 + quad * 4 + r;
                if (grow < VOCAB) sc[grow] = scl[r];
            }
        }
    }
    __syncthreads();
    #pragma unroll
    for (int i = 0; i < 8; ++i) {
        const int idx = i * 64 + lane;        // 0..511
        const int row = idx >> 3;
        const int p   = idx & 7;
        const int grow = m_base + row;
        const uint4 v = *(const uint4*)(st + row * 128 + p * 16);
        if (grow < VOCAB)
            *(uint4*)(qt + (size_t)grow * HH + p * 16) = v;
    }
}

// ---------------- pass B: gather (1 line/row) + tiny MLP ----------------
// One block per sample, 4 waves. Lane l: g=l>>3 selects the row slot, p=l&7
// selects 16 B of the 128-B row -> 8 rows per wave-instruction, each row is
// exactly one cache line. Indices bitonic-sorted (L3/L2 locality). W1 GEMV is
// gone: h = relu(rep'/len + b1).
__global__ __launch_bounds__(256) void fused_gather_q8(
    const int*           __restrict__ x,
    const int*           __restrict__ lengths,
    const unsigned char* __restrict__ qt,
    const float*         __restrict__ sc,
    const float*         __restrict__ b1,
    const float*         __restrict__ W2,
    const float*         __restrict__ b2,
    float*               __restrict__ out)
{
    __shared__ int   idx_s[NSRT];
    __shared__ float part_f[32 * HH];    // [wave*8+g][128 ch]
    __shared__ float h_s[HH];

    const int b = blockIdx.x;
    const int t = threadIdx.x;
    const int w = t >> 6;
    const int l = t & 63;

    idx_s[t] = (t < LL) ? x[b * LL + t] : 0x7FFFFFFF;
    __syncthreads();

    #pragma unroll
    for (int k = 2; k <= NSRT; k <<= 1) {
        #pragma unroll
        for (int j = k >> 1; j > 0; j >>= 1) {
            const int ixj = t ^ j;
            if (ixj > t) {
                const int a0 = idx_s[t];
                const int a1 = idx_s[ixj];
                const bool up = ((t & k) == 0);
                if ((a0 > a1) == up) { idx_s[t] = a1; idx_s[ixj] = a0; }
            }
            __syncthreads();
        }
    }

    const int g = l >> 3;                // row-slot offset 0..7
    const int p = l & 7;                 // 16-B chunk 0..7

    float4 a0 = make_float4(0.f,0.f,0.f,0.f);
    float4 a1 = make_float4(0.f,0.f,0.f,0.f);
    float4 a2 = make_float4(0.f,0.f,0.f,0.f);
    float4 a3 = make_float4(0.f,0.f,0.f,0.f);

    #pragma unroll
    for (int i = 0; i < 7; ++i) {        // j = 8i+g covers 0..55 >= RPW
        const int j  = 8 * i + g;
        const int jc = (j < RPW) ? j : (RPW - 1);
        const int ridx = idx_s[w + 4 * jc];           // wave-interleaved sorted
        const uint4 d = *(const uint4*)(qt + (size_t)ridx * HH + (p << 4));
        const float sv = (j < RPW) ? sc[ridx] : 0.f;

        a0.x = fmaf(sv, (float)(signed char)(d.x       ), a0.x);
        a0.y = fmaf(sv, (float)(signed char)(d.x >>  8 ), a0.y);
        a0.z = fmaf(sv, (float)(signed char)(d.x >> 16 ), a0.z);
        a0.w = fmaf(sv, (float)(signed char)(d.x >> 24 ), a0.w);
        a1.x = fmaf(sv, (float)(signed char)(d.y       ), a1.x);
        a1.y = fmaf(sv, (float)(signed char)(d.y >>  8 ), a1.y);
        a1.z = fmaf(sv, (float)(signed char)(d.y >> 16 ), a1.z);
        a1.w = fmaf(sv, (float)(signed char)(d.y >> 24 ), a1.w);
        a2.x = fmaf(sv, (float)(signed char)(d.z       ), a2.x);
        a2.y = fmaf(sv, (float)(signed char)(d.z >>  8 ), a2.y);
        a2.z = fmaf(sv, (float)(signed char)(d.z >> 16 ), a2.z);
        a2.w = fmaf(sv, (float)(signed char)(d.z >> 24 ), a2.w);
        a3.x = fmaf(sv, (float)(signed char)(d.w       ), a3.x);
        a3.y = fmaf(sv, (float)(signed char)(d.w >>  8 ), a3.y);
        a3.z = fmaf(sv, (float)(signed char)(d.w >> 16 ), a3.z);
        a3.w = fmaf(sv, (float)(signed char)(d.w >> 24 ), a3.w);
    }

    {
        float* dst = &part_f[(w * 8 + g) * HH + p * 16];
        *(float4*)(dst + 0)  = a0;
        *(float4*)(dst + 4)  = a1;
        *(float4*)(dst + 8)  = a2;
        *(float4*)(dst + 12) = a3;
    }
    __syncthreads();

    const float inv_len = 1.0f / (float)lengths[b];
    if (t < HH) {
        float s = 0.f;
        #pragma unroll
        for (int q = 0; q < 32; ++q) s += part_f[q * HH + t];
        h_s[t] = fmaxf(fmaf(s, inv_len, b1[t]), 0.f);
    }
    __syncthreads();

    if (t < OUTD) {
        float oacc = b2[t];
        #pragma unroll
        for (int k = 0; k < HH; ++k)
            oacc = fmaf(h_s[k], W2[k * OUTD + t], oacc);
        out[b * OUTD + t] = oacc;
    }
}

// ---------------- fallback (ws too small): proven fp32 path ----------------
__global__ __launch_bounds__(256) void fused_dnn_f32(
    const int* __restrict__ x, const int* __restrict__ lengths,
    const float* __restrict__ table, const float* __restrict__ W1,
    const float* __restrict__ b1, const float* __restrict__ W2,
    const float* __restrict__ b2, float* __restrict__ out)
{
    __shared__ int    idx_s[NSRT];
    __shared__ float4 part_s[4][76];
    __shared__ float  rep_s[EMB];
    __shared__ float  h_part[2][HH];
    __shared__ float  h_s[HH];

    const int b = blockIdx.x, t = threadIdx.x, w = t >> 6, lane = t & 63;
    idx_s[t] = (t < LL) ? x[b * LL + t] : 0x7FFFFFFF;
    __syncthreads();
    #pragma unroll
    for (int k = 2; k <= NSRT; k <<= 1)
        #pragma unroll
        for (int j = k >> 1; j > 0; j >>= 1) {
            const int ixj = t ^ j;
            if (ixj > t) {
                const int q0 = idx_s[t], q1 = idx_s[ixj];
                const bool up = ((t & k) == 0);
                if ((q0 > q1) == up) { idx_s[t] = q1; idx_s[ixj] = q0; }
            }
            __syncthreads();
        }
    const int myidx = (lane < RPW) ? idx_s[w + 4 * lane] : 0;
    float4 acc_a = make_float4(0.f,0.f,0.f,0.f);
    float4 acc_b = make_float4(0.f,0.f,0.f,0.f);
    const bool hasb = (lane < (EMB / 4 - 64));
    #pragma unroll 5
    for (int i = 0; i < RPW; ++i) {
        const int ridx = __builtin_amdgcn_readlane(myidx, i);
        const float4* row = (const float4*)(table + (size_t)ridx * EMB);
        float4 va = row[lane];
        acc_a.x += va.x; acc_a.y += va.y; acc_a.z += va.z; acc_a.w += va.w;
        if (hasb) {
            float4 vb = row[64 + lane];
            acc_b.x += vb.x; acc_b.y += vb.y; acc_b.z += vb.z; acc_b.w += vb.w;
        }
    }
    part_s[w][lane] = acc_a;
    if (hasb) part_s[w][64 + lane] = acc_b;
    __syncthreads();
    const float inv_len = 1.0f / (float)lengths[b];
    const float* ps = (const float*)part_s;
    { float sv = ps[t]+ps[304+t]+ps[608+t]+ps[912+t]; rep_s[t] = sv*inv_len; }
    if (t < (EMB-256)) { int c=256+t; float sv=ps[c]+ps[304+c]+ps[608+c]+ps[912+c]; rep_s[c]=sv*inv_len; }
    __syncthreads();
    { const int half=t>>7, col=t&127; float hacc=(half==0)?b1[col]:0.f; const int k0=half*(EMB/2);
      #pragma unroll 5
      for (int k=k0;k<k0+EMB/2;++k) hacc=fmaf(rep_s[k],W1[k*HH+col],hacc);
      h_part[half][col]=hacc; }
    __syncthreads();
    if (t<HH) h_s[t]=fmaxf(h_part[0][t]+h_part[1][t],0.f);
    __syncthreads();
    if (t<OUTD) { float o=b2[t];
        #pragma unroll
        for (int k=0;k<HH;++k) o=fmaf(h_s[k],W2[k*OUTD+t],o);
        out[b*OUTD+t]=o; }
}

extern "C" void kernel_launch(void* const* d_in, const int* in_sizes, int n_in,
                              void* d_out, int out_size, void* d_ws, size_t ws_size,
                              hipStream_t stream) {
    const int*   x       = (const int*)  d_in[0];
    const int*   lengths = (const int*)  d_in[1];
    const float* table   = (const float*)d_in[2];
    const float* W1      = (const float*)d_in[3];
    const float* b1      = (const float*)d_in[4];
    const float* W2      = (const float*)d_in[5];
    const float* b2      = (const float*)d_in[6];
    float*       out     = (float*)d_out;

    if (ws_size >= WS_NEED) {
        unsigned char* qt = (unsigned char*)d_ws;
        float*         sc = (float*)((char*)d_ws + SC_OFF);
        proj_quant<<<(VOCAB + 255) / 256, 256, 0, stream>>>(table, W1, qt, sc);
        fused_gather_q8<<<BB, 256, 0, stream>>>(x, lengths, qt, sc, b1, W2, b2, out);
    } else {
        fused_dnn_f32<<<BB, 256, 0, stream>>>(x, lengths, table, W1, b1, W2, b2, out);
    }
}